// Round 1
// baseline (683.373 us; speedup 1.0000x reference)
//
#include <hip/hip_runtime.h>

#define C_S 384
#define C_Z 128
#define N_SEQ 1024

// Kernel 1: per-row projections si[n] = dot(s[n], Wi), sj[n] = dot(s[n], Wj) + b.
// One wave per row n. 4 waves per 256-thread block -> 256 blocks. Tiny (~1.5 MB read).
__global__ __launch_bounds__(256) void sisj_kernel(const float* __restrict__ s,
                                                   const float* __restrict__ W,
                                                   const float* __restrict__ b,
                                                   float* __restrict__ si,
                                                   float* __restrict__ sj) {
    const int lane = threadIdx.x & 63;
    const int wave = threadIdx.x >> 6;
    const int n = blockIdx.x * 4 + wave;

    const float* srow = s + (size_t)n * C_S;
    const float* Wi = W;          // W[0, 0:384]
    const float* Wj = W + C_S;    // W[0, 384:768]

    float acc_i = 0.f, acc_j = 0.f;
#pragma unroll
    for (int j = 0; j < C_S / 64; ++j) {
        const int idx = lane + 64 * j;
        const float v = srow[idx];
        acc_i += v * Wi[idx];
        acc_j += v * Wj[idx];
    }
#pragma unroll
    for (int mask = 32; mask >= 1; mask >>= 1) {
        acc_i += __shfl_xor(acc_i, mask);
        acc_j += __shfl_xor(acc_j, mask);
    }
    if (lane == 0) {
        si[n] = acc_i;
        sj[n] = acc_j + b[0];
    }
}

// Kernel 2: out[o] = dot(z[o, 0:128], Wz) + si[o>>10] + sj[o&1023].
//
// Persistent-wave grid-stride version. Each wave processes a CHUNK of
// U_PAIRS=8 consecutive output-pairs per iteration:
//   - pair p = 2 outputs (2*p, 2*p+1) = 256 consecutive floats of z (1 KiB).
//   - lane layout within a pair: lanes 0-31 -> output 2p   (channels 4l..4l+3),
//                                lanes 32-63 -> output 2p+1.
//     The wave's 64 x 16B loads cover one contiguous 1 KiB segment.
//   - 8 independent float4 loads are issued back-to-back (8 KiB contiguous per
//     wave-iteration) before any reduction -> 8 loads in flight per wave,
//     hiding HBM latency without relying on block churn.
// Grid = 2048 blocks (8 blocks/CU x 256 CU), 8192 waves, 65536 chunks ->
// exactly 8 chunk-iterations per wave. No dispatch-rate bottleneck.
#define U_PAIRS 8
#define CONTACT_BLOCKS 2048

__global__ __launch_bounds__(256) void contact_kernel(const float* __restrict__ z,
                                                      const float* __restrict__ W,
                                                      const float* __restrict__ si,
                                                      const float* __restrict__ sj,
                                                      float* __restrict__ out) {
    const int lane = threadIdx.x & 63;
    const int wave = threadIdx.x >> 6;
    const int half = lane >> 5;        // which output of the pair
    const int l = lane & 31;           // position within the 32-lane reduction group
    const int gw = blockIdx.x * 4 + wave;      // global wave id, 0..8191
    const int nwaves = CONTACT_BLOCKS * 4;     // 8192

    // Wz fragment for this lane's channel slice (same for all waves; L1/L2 resident)
    const float4 wz = *(const float4*)(W + 2 * C_S + 4 * l);

    const int NPAIRS = (N_SEQ * N_SEQ) / 2;    // 524288
    const int NCHUNK = NPAIRS / U_PAIRS;       // 65536

    for (int c = gw; c < NCHUNK; c += nwaves) {
        // Base of this chunk: U_PAIRS pairs * 256 floats, this lane's 16B slice.
        const float* zb = z + (size_t)c * (U_PAIRS * 256) + 4 * lane;

        float4 z4[U_PAIRS];
#pragma unroll
        for (int u = 0; u < U_PAIRS; ++u) {
            z4[u] = *(const float4*)(zb + u * 256);
        }

        float p[U_PAIRS];
#pragma unroll
        for (int u = 0; u < U_PAIRS; ++u) {
            p[u] = z4[u].x * wz.x + z4[u].y * wz.y + z4[u].z * wz.z + z4[u].w * wz.w;
        }

        // Reduce across each 32-lane half. masks <=16 never cross the half
        // boundary. Interleave the U_PAIRS reductions so the 8 shuffle chains
        // overlap (independent DS ops -> latency hidden by ILP).
#pragma unroll
        for (int mask = 16; mask >= 1; mask >>= 1) {
#pragma unroll
            for (int u = 0; u < U_PAIRS; ++u) {
                p[u] += __shfl_xor(p[u], mask);
            }
        }

        if (l == 0) {
            // Outputs for this chunk: o = (c*U_PAIRS + u)*2 + half
#pragma unroll
            for (int u = 0; u < U_PAIRS; ++u) {
                const long long o = (((long long)c * U_PAIRS + u) << 1) + half;
                const int n = (int)(o >> 10);
                const int m = (int)(o & 1023);
                out[o] = p[u] + si[n] + sj[m];
            }
        }
    }
}

extern "C" void kernel_launch(void* const* d_in, const int* in_sizes, int n_in,
                              void* d_out, int out_size, void* d_ws, size_t ws_size,
                              hipStream_t stream) {
    const float* s = (const float*)d_in[0];   // (1,1024,384)
    const float* z = (const float*)d_in[1];   // (1,1024,1024,128)
    const float* W = (const float*)d_in[2];   // (1,896)
    const float* b = (const float*)d_in[3];   // (1,)
    float* out = (float*)d_out;               // (1,1024,1024,1)

    float* si = (float*)d_ws;                 // 1024 floats
    float* sj = si + N_SEQ;                   // 1024 floats

    // 1024 rows, one wave each, 4 waves/block
    sisj_kernel<<<N_SEQ / 4, 256, 0, stream>>>(s, W, b, si, sj);

    // Persistent grid: 2048 blocks = 8 blocks/CU x 256 CUs
    contact_kernel<<<CONTACT_BLOCKS, 256, 0, stream>>>(z, W, si, sj, out);
}